// Round 4
// baseline (173.627 us; speedup 1.0000x reference)
//
#include <hip/hip_runtime.h>
#include <math.h>

#define NPIX (512 * 512)
#define KCLS 16
#define NB   4
#define EPSF 1e-5f
#define D_LOG_2PI 1.8378770664093453

// ---------------------------------------------------------------------------
// Kernel 1: per-(b,k) raw moments. Each block owns a 2048-pixel chunk of one
// batch image, preloads I into registers (reused across all 16 classes), and
// loops k accumulating 10 stats: SP, S1[3], S2[6]. Wave shuffle-reduce ->
// LDS cross-wave reduce -> one fp64 atomicAdd per stat per block.
// grid: (NPIX/2048, NB), block 256.
// ---------------------------------------------------------------------------
__global__ __launch_bounds__(256)
void k_stats(const float* __restrict__ P, const float* __restrict__ I,
             double* __restrict__ stats) {
    const int tid  = threadIdx.x;
    const int b    = blockIdx.y;
    const int base = blockIdx.x * 2048;
    const float* Ib = I + (size_t)b * 3 * NPIX;

    // preload image chunk: 2 iters x 3 channels x float4 = 24 VGPRs
    float xr[2][4], yr[2][4], zr[2][4];
#pragma unroll
    for (int it = 0; it < 2; ++it) {
        const int px = base + it * 1024 + tid * 4;
        *(float4*)xr[it] = *(const float4*)(Ib + px);
        *(float4*)yr[it] = *(const float4*)(Ib + NPIX + px);
        *(float4*)zr[it] = *(const float4*)(Ib + 2 * NPIX + px);
    }

    __shared__ float red[4][10];
    const int wave = tid >> 6, lane = tid & 63;

    for (int k = 0; k < KCLS; ++k) {
        const float* Pk = P + (size_t)(b * KCLS + k) * NPIX + base;
        float s[10];
#pragma unroll
        for (int j = 0; j < 10; ++j) s[j] = 0.f;

#pragma unroll
        for (int it = 0; it < 2; ++it) {
            float pv[4];
            *(float4*)pv = *(const float4*)(Pk + it * 1024 + tid * 4);
#pragma unroll
            for (int j = 0; j < 4; ++j) {
                const float p = pv[j];
                const float x = xr[it][j], y = yr[it][j], z = zr[it][j];
                const float px_ = p * x, py_ = p * y, pz_ = p * z;
                s[0] += p;
                s[1] += px_;      s[2] += py_;      s[3] += pz_;
                s[4] += px_ * x;  s[5] += px_ * y;  s[6] += px_ * z;
                s[7] += py_ * y;  s[8] += py_ * z;  s[9] += pz_ * z;
            }
        }
        // 64-lane wave reduction
#pragma unroll
        for (int j = 0; j < 10; ++j) {
            float v = s[j];
#pragma unroll
            for (int off = 32; off > 0; off >>= 1)
                v += __shfl_down(v, off);
            if (lane == 0) red[wave][j] = v;
        }
        __syncthreads();
        if (tid < 10) {
            const float v = red[0][tid] + red[1][tid] + red[2][tid] + red[3][tid];
            atomicAdd(&stats[(size_t)(b * KCLS + k) * 10 + tid], (double)v);
        }
        __syncthreads();  // protect LDS reuse for next k
    }
}

// ---------------------------------------------------------------------------
// Kernel 2: 64 (b,k) pairs. fp64: covariance from raw moments (+1e-3 jitter),
// symmetric 3x3 adjugate inverse, logdet; fold alpha * exp(-0.5*(3*LOG_2PI +
// logdet)) into a single coefficient. Emits 10 fp32 params per pair:
// [mu0,mu1,mu2, i00,i01,i02,i11,i12,i22, coeff]
// ---------------------------------------------------------------------------
__global__ void k_params(const double* __restrict__ stats,
                         float* __restrict__ params) {
    const int idx = threadIdx.x;
    if (idx >= NB * KCLS) return;
    const double* s = stats + (size_t)idx * 10;
    const double SP    = s[0];
    const double denom = 1e-5 + SP;
    const double alpha = SP / (double)NPIX;
    const double m0 = s[1] / denom, m1 = s[2] / denom, m2 = s[3] / denom;
    const double c00 = (s[4] - 2.0 * m0 * s[1] + m0 * m0 * SP) / denom + 1e-3;
    const double c01 = (s[5] - m0 * s[2] - m1 * s[1] + m0 * m1 * SP) / denom;
    const double c02 = (s[6] - m0 * s[3] - m2 * s[1] + m0 * m2 * SP) / denom;
    const double c11 = (s[7] - 2.0 * m1 * s[2] + m1 * m1 * SP) / denom + 1e-3;
    const double c12 = (s[8] - m1 * s[3] - m2 * s[2] + m1 * m2 * SP) / denom;
    const double c22 = (s[9] - 2.0 * m2 * s[3] + m2 * m2 * SP) / denom + 1e-3;
    // symmetric adjugate
    const double A00 = c11 * c22 - c12 * c12;
    const double A01 = c02 * c12 - c01 * c22;
    const double A02 = c01 * c12 - c02 * c11;
    const double A11 = c00 * c22 - c02 * c02;
    const double A12 = c01 * c02 - c00 * c12;
    const double A22 = c00 * c11 - c01 * c01;
    const double det = c00 * A00 + c01 * A01 + c02 * A02;
    const double coeff = alpha * exp(-0.5 * (3.0 * D_LOG_2PI + log(det)));
    float* o = params + (size_t)idx * 10;
    o[0] = (float)m0;          o[1] = (float)m1;          o[2] = (float)m2;
    o[3] = (float)(A00 / det); o[4] = (float)(A01 / det); o[5] = (float)(A02 / det);
    o[6] = (float)(A11 / det); o[7] = (float)(A12 / det); o[8] = (float)(A22 / det);
    o[9] = (float)coeff;
}

// ---------------------------------------------------------------------------
// Kernel 3: E-step + row normalization. Per pixel: 16 Mahalanobis quads +
// exp, normalize by (eps + sum_k Q), 16 float4 coalesced stores. Never reads
// Pij. grid: (NPIX/1024, NB), block 256, 4 px/thread.
// ---------------------------------------------------------------------------
__global__ __launch_bounds__(256)
void k_estep(const float* __restrict__ I, const float* __restrict__ params,
             float* __restrict__ out) {
    const int b = blockIdx.y;
    __shared__ float pp[KCLS * 10];
    if (threadIdx.x < KCLS * 10)
        pp[threadIdx.x] = params[b * KCLS * 10 + threadIdx.x];
    __syncthreads();

    const int px = blockIdx.x * 1024 + threadIdx.x * 4;
    const float* Ib = I + (size_t)b * 3 * NPIX;
    float x[4], y[4], z[4];
    *(float4*)x = *(const float4*)(Ib + px);
    *(float4*)y = *(const float4*)(Ib + NPIX + px);
    *(float4*)z = *(const float4*)(Ib + 2 * NPIX + px);

    float q[KCLS][4];
    float sum[4] = {0.f, 0.f, 0.f, 0.f};
#pragma unroll
    for (int k = 0; k < KCLS; ++k) {
        const float m0  = pp[k * 10 + 0], m1  = pp[k * 10 + 1], m2  = pp[k * 10 + 2];
        const float i00 = pp[k * 10 + 3], i01 = pp[k * 10 + 4], i02 = pp[k * 10 + 5];
        const float i11 = pp[k * 10 + 6], i12 = pp[k * 10 + 7], i22 = pp[k * 10 + 8];
        const float cf  = pp[k * 10 + 9];
#pragma unroll
        for (int j = 0; j < 4; ++j) {
            const float d0 = x[j] - m0, d1 = y[j] - m1, d2 = z[j] - m2;
            const float quad = i00 * d0 * d0 + i11 * d1 * d1 + i22 * d2 * d2
                             + 2.f * (i01 * d0 * d1 + i02 * d0 * d2 + i12 * d1 * d2);
            const float qv = cf * __expf(-0.5f * quad);
            q[k][j] = qv;
            sum[j] += qv;
        }
    }
    float inv[4];
#pragma unroll
    for (int j = 0; j < 4; ++j) inv[j] = 1.f / (EPSF + sum[j]);
#pragma unroll
    for (int k = 0; k < KCLS; ++k) {
        float4 o;
        o.x = q[k][0] * inv[0];
        o.y = q[k][1] * inv[1];
        o.z = q[k][2] * inv[2];
        o.w = q[k][3] * inv[3];
        *(float4*)(out + (size_t)(b * KCLS + k) * NPIX + px) = o;
    }
}

// ---------------------------------------------------------------------------
extern "C" void kernel_launch(void* const* d_in, const int* in_sizes, int n_in,
                              void* d_out, int out_size, void* d_ws, size_t ws_size,
                              hipStream_t stream) {
    const float* Pij = (const float*)d_in[0];
    const float* I   = (const float*)d_in[1];
    float* out = (float*)d_out;

    double* stats = (double*)d_ws;                                   // 64*10 fp64
    float* params = (float*)((char*)d_ws + NB * KCLS * 10 * sizeof(double));

    // ws is re-poisoned to 0xAA before every launch — zero the accumulators.
    hipMemsetAsync(stats, 0, NB * KCLS * 10 * sizeof(double), stream);

    k_stats <<<dim3(NPIX / 2048, NB), 256, 0, stream>>>(Pij, I, stats);
    k_params<<<1, 64, 0, stream>>>(stats, params);
    k_estep <<<dim3(NPIX / 1024, NB), 256, 0, stream>>>(I, params, out);
}

// Round 5
// 140.658 us; speedup vs baseline: 1.2344x; 1.2344x over previous
//
#include <hip/hip_runtime.h>
#include <math.h>

#define NPIX (512 * 512)
#define KCLS 16
#define NB   4
#define EPSF 1e-5f
#define D_LOG_2PI 1.8378770664093453

// ---------------------------------------------------------------------------
// Kernel 1 (restructured round 4): raw moments, one (b,k) pair per blockIdx.y,
// 32 pixel-chunks per blockIdx.x. Each block streams 8192 contiguous pixels
// (32 px/thread, fully unrolled -> 32 independent float4 loads in flight),
// accumulates 10 stats in registers, reduces ONCE per block (vs 16x before:
// that per-k shuffle chain was the 68 us latency bound, VALUBusy 12%).
// I is re-read per k but is L2/L3-resident (12 MB; profile showed L3 already
// absorbing). grid: (32, NB*KCLS) = 2048 blocks = 8 blocks/CU -> full occ.
// ---------------------------------------------------------------------------
__global__ __launch_bounds__(256)
void k_stats(const float* __restrict__ P, const float* __restrict__ I,
             double* __restrict__ stats) {
    const int tid  = threadIdx.x;
    const int bk   = blockIdx.y;          // 0..63 == b*KCLS + k
    const int b    = bk >> 4;
    const int base = blockIdx.x * 8192;
    const float* Pk = P + (size_t)bk * NPIX + base;
    const float* Ib = I + (size_t)b * 3 * NPIX + base;

    float s[10];
#pragma unroll
    for (int j = 0; j < 10; ++j) s[j] = 0.f;

#pragma unroll
    for (int it = 0; it < 8; ++it) {
        const int off = it * 1024 + tid * 4;
        float pv[4], xv[4], yv[4], zv[4];
        *(float4*)pv = *(const float4*)(Pk + off);
        *(float4*)xv = *(const float4*)(Ib + off);
        *(float4*)yv = *(const float4*)(Ib + NPIX + off);
        *(float4*)zv = *(const float4*)(Ib + 2 * NPIX + off);
#pragma unroll
        for (int j = 0; j < 4; ++j) {
            const float p = pv[j];
            const float x = xv[j], y = yv[j], z = zv[j];
            const float px_ = p * x, py_ = p * y, pz_ = p * z;
            s[0] += p;
            s[1] += px_;      s[2] += py_;      s[3] += pz_;
            s[4] += px_ * x;  s[5] += px_ * y;  s[6] += px_ * z;
            s[7] += py_ * y;  s[8] += py_ * z;  s[9] += pz_ * z;
        }
    }

    // single per-block reduction: 64-lane shuffle tree -> LDS cross-wave -> atomic
    __shared__ float red[4][10];
    const int wave = tid >> 6, lane = tid & 63;
#pragma unroll
    for (int j = 0; j < 10; ++j) {
        float v = s[j];
#pragma unroll
        for (int off = 32; off > 0; off >>= 1)
            v += __shfl_down(v, off);
        if (lane == 0) red[wave][j] = v;
    }
    __syncthreads();
    if (tid < 10) {
        const float v = red[0][tid] + red[1][tid] + red[2][tid] + red[3][tid];
        atomicAdd(&stats[(size_t)bk * 10 + tid], (double)v);
    }
}

// ---------------------------------------------------------------------------
// Kernel 2: 64 (b,k) pairs. fp64: covariance from raw moments (+1e-3 jitter),
// symmetric 3x3 adjugate inverse, logdet; fold alpha * exp(-0.5*(3*LOG_2PI +
// logdet)) into a single coefficient. Emits 10 fp32 params per pair:
// [mu0,mu1,mu2, i00,i01,i02,i11,i12,i22, coeff]
// ---------------------------------------------------------------------------
__global__ void k_params(const double* __restrict__ stats,
                         float* __restrict__ params) {
    const int idx = threadIdx.x;
    if (idx >= NB * KCLS) return;
    const double* s = stats + (size_t)idx * 10;
    const double SP    = s[0];
    const double denom = 1e-5 + SP;
    const double alpha = SP / (double)NPIX;
    const double m0 = s[1] / denom, m1 = s[2] / denom, m2 = s[3] / denom;
    const double c00 = (s[4] - 2.0 * m0 * s[1] + m0 * m0 * SP) / denom + 1e-3;
    const double c01 = (s[5] - m0 * s[2] - m1 * s[1] + m0 * m1 * SP) / denom;
    const double c02 = (s[6] - m0 * s[3] - m2 * s[1] + m0 * m2 * SP) / denom;
    const double c11 = (s[7] - 2.0 * m1 * s[2] + m1 * m1 * SP) / denom + 1e-3;
    const double c12 = (s[8] - m1 * s[3] - m2 * s[2] + m1 * m2 * SP) / denom;
    const double c22 = (s[9] - 2.0 * m2 * s[3] + m2 * m2 * SP) / denom + 1e-3;
    // symmetric adjugate
    const double A00 = c11 * c22 - c12 * c12;
    const double A01 = c02 * c12 - c01 * c22;
    const double A02 = c01 * c12 - c02 * c11;
    const double A11 = c00 * c22 - c02 * c02;
    const double A12 = c01 * c02 - c00 * c12;
    const double A22 = c00 * c11 - c01 * c01;
    const double det = c00 * A00 + c01 * A01 + c02 * A02;
    const double coeff = alpha * exp(-0.5 * (3.0 * D_LOG_2PI + log(det)));
    float* o = params + (size_t)idx * 10;
    o[0] = (float)m0;          o[1] = (float)m1;          o[2] = (float)m2;
    o[3] = (float)(A00 / det); o[4] = (float)(A01 / det); o[5] = (float)(A02 / det);
    o[6] = (float)(A11 / det); o[7] = (float)(A12 / det); o[8] = (float)(A22 / det);
    o[9] = (float)coeff;
}

// ---------------------------------------------------------------------------
// Kernel 3: E-step + row normalization. Per pixel: 16 Mahalanobis quads +
// exp, normalize by (eps + sum_k Q), 16 float4 coalesced stores. Never reads
// Pij. grid: (NPIX/1024, NB), block 256, 4 px/thread.
// (unchanged this round — need its clean dispatch time in the next profile)
// ---------------------------------------------------------------------------
__global__ __launch_bounds__(256)
void k_estep(const float* __restrict__ I, const float* __restrict__ params,
             float* __restrict__ out) {
    const int b = blockIdx.y;
    __shared__ float pp[KCLS * 10];
    if (threadIdx.x < KCLS * 10)
        pp[threadIdx.x] = params[b * KCLS * 10 + threadIdx.x];
    __syncthreads();

    const int px = blockIdx.x * 1024 + threadIdx.x * 4;
    const float* Ib = I + (size_t)b * 3 * NPIX;
    float x[4], y[4], z[4];
    *(float4*)x = *(const float4*)(Ib + px);
    *(float4*)y = *(const float4*)(Ib + NPIX + px);
    *(float4*)z = *(const float4*)(Ib + 2 * NPIX + px);

    float q[KCLS][4];
    float sum[4] = {0.f, 0.f, 0.f, 0.f};
#pragma unroll
    for (int k = 0; k < KCLS; ++k) {
        const float m0  = pp[k * 10 + 0], m1  = pp[k * 10 + 1], m2  = pp[k * 10 + 2];
        const float i00 = pp[k * 10 + 3], i01 = pp[k * 10 + 4], i02 = pp[k * 10 + 5];
        const float i11 = pp[k * 10 + 6], i12 = pp[k * 10 + 7], i22 = pp[k * 10 + 8];
        const float cf  = pp[k * 10 + 9];
#pragma unroll
        for (int j = 0; j < 4; ++j) {
            const float d0 = x[j] - m0, d1 = y[j] - m1, d2 = z[j] - m2;
            const float quad = i00 * d0 * d0 + i11 * d1 * d1 + i22 * d2 * d2
                             + 2.f * (i01 * d0 * d1 + i02 * d0 * d2 + i12 * d1 * d2);
            const float qv = cf * __expf(-0.5f * quad);
            q[k][j] = qv;
            sum[j] += qv;
        }
    }
    float inv[4];
#pragma unroll
    for (int j = 0; j < 4; ++j) inv[j] = 1.f / (EPSF + sum[j]);
#pragma unroll
    for (int k = 0; k < KCLS; ++k) {
        float4 o;
        o.x = q[k][0] * inv[0];
        o.y = q[k][1] * inv[1];
        o.z = q[k][2] * inv[2];
        o.w = q[k][3] * inv[3];
        *(float4*)(out + (size_t)(b * KCLS + k) * NPIX + px) = o;
    }
}

// ---------------------------------------------------------------------------
extern "C" void kernel_launch(void* const* d_in, const int* in_sizes, int n_in,
                              void* d_out, int out_size, void* d_ws, size_t ws_size,
                              hipStream_t stream) {
    const float* Pij = (const float*)d_in[0];
    const float* I   = (const float*)d_in[1];
    float* out = (float*)d_out;

    double* stats = (double*)d_ws;                                   // 64*10 fp64
    float* params = (float*)((char*)d_ws + NB * KCLS * 10 * sizeof(double));

    // ws is re-poisoned to 0xAA before every launch — zero the accumulators.
    hipMemsetAsync(stats, 0, NB * KCLS * 10 * sizeof(double), stream);

    k_stats <<<dim3(32, NB * KCLS), 256, 0, stream>>>(Pij, I, stats);
    k_params<<<1, 64, 0, stream>>>(stats, params);
    k_estep <<<dim3(NPIX / 1024, NB), 256, 0, stream>>>(I, params, out);
}